// Round 1
// baseline (722.126 us; speedup 1.0000x reference)
//
#include <hip/hip_runtime.h>
#include <stdint.h>

// ---------------- problem constants ----------------
#define E_DIM   1024
#define H_NUM   16
#define HD      64        // head dim
#define F_DIM   4096
#define B_NUM   4
#define S_LEN   2048
#define M_ROWS  (B_NUM * S_LEN)   // 8192

typedef unsigned short u16;
typedef __bf16 bf16_t;
typedef bf16_t  bf16x8 __attribute__((ext_vector_type(8)));
typedef u16     u16x8  __attribute__((ext_vector_type(8)));
typedef float   f32x4  __attribute__((ext_vector_type(4)));

#define AS1 __attribute__((address_space(1)))
#define AS3 __attribute__((address_space(3)))

// async global->LDS, 16B per lane, wave-uniform LDS base + lane*16
__device__ __forceinline__ void gload_lds16(const void* g, void* l) {
    __builtin_amdgcn_global_load_lds((AS1 void*)g, (AS3 void*)l, 16, 0, 0);
}

// f32 -> bf16 RNE
__device__ __forceinline__ u16 f2b(float f) {
    union { float f; unsigned u; } a; a.f = f;
    unsigned u = a.u + 0x7fffu + ((a.u >> 16) & 1u);
    return (u16)(u >> 16);
}

// ---------------- cast kernel ----------------
__global__ __launch_bounds__(256) void cast_f32_bf16(const float* __restrict__ in,
                                                     u16* __restrict__ out, int n4) {
    int stride = gridDim.x * blockDim.x;
    for (int i = blockIdx.x * blockDim.x + threadIdx.x; i < n4; i += stride) {
        float4 v = reinterpret_cast<const float4*>(in)[i];
        ushort4 o;
        o.x = f2b(v.x); o.y = f2b(v.y); o.z = f2b(v.z); o.w = f2b(v.w);
        reinterpret_cast<ushort4*>(out)[i] = o;
    }
}

// ---------------- GEMM: C[M,N] = A[M,K] * B[N,K]^T ----------------
// 128x128 tile, BK=64, 256 threads (4 waves as 2x2, each 64x64 output).
// LDS tile: 128 rows x 64 cols bf16 = 16KB, staged via global_load_lds w16.
__device__ __forceinline__ void stage_tile128(const char* gbase, int ldk_elems,
                                              char* lds, int wave, int lane) {
    // tile = 16KB = 16 x 1KB wave-instructions, 4 per wave
#pragma unroll
    for (int j = 0; j < 4; ++j) {
        int ob   = (wave * 4 + j) * 1024 + lane * 16;   // byte offset in tile
        int row  = ob >> 7;                              // 128 B per row
        int colb = ob & 127;
        const char* gp = gbase + (size_t)row * ((size_t)ldk_elems * 2) + colb;
        char* lp = lds + (wave * 4 + j) * 1024;          // wave-uniform base
        gload_lds16(gp, lp);
    }
}

__device__ __forceinline__ void store_c(float* C, size_t idx, float v) { C[idx] = v; }
__device__ __forceinline__ void store_c(u16* C, size_t idx, float v)   { C[idx] = f2b(v); }

template <typename OutT, bool RELU, bool HASBIAS>
__global__ __launch_bounds__(256)
void gemm_bt(const u16* __restrict__ A, const u16* __restrict__ B,
             OutT* __restrict__ C, const float* __restrict__ bias,
             int M, int N, int K) {
    __shared__ char As[128 * 64 * 2];
    __shared__ char Bs[128 * 64 * 2];
    const int tid  = threadIdx.x;
    const int lane = tid & 63, wave = tid >> 6;
    const int lr   = lane & 15, kh = lane >> 4;
    const int row0 = blockIdx.y * 128, col0 = blockIdx.x * 128;
    const int wm   = wave >> 1, wn = wave & 1;

    f32x4 acc[4][4];
#pragma unroll
    for (int mi = 0; mi < 4; ++mi)
#pragma unroll
        for (int ni = 0; ni < 4; ++ni) acc[mi][ni] = (f32x4){0.f, 0.f, 0.f, 0.f};

    for (int kt = 0; kt < K; kt += 64) {
        stage_tile128((const char*)(A + (size_t)row0 * K + kt), K, As, wave, lane);
        stage_tile128((const char*)(B + (size_t)col0 * K + kt), K, Bs, wave, lane);
        __syncthreads();   // drains vmcnt for global_load_lds
#pragma unroll
        for (int kk = 0; kk < 2; ++kk) {
            bf16x8 af[4], bfr[4];
#pragma unroll
            for (int mi = 0; mi < 4; ++mi)
                af[mi] = *(const bf16x8*)(As + ((size_t)(wm * 64 + mi * 16 + lr) * 64 + kk * 32 + kh * 8) * 2);
#pragma unroll
            for (int ni = 0; ni < 4; ++ni)
                bfr[ni] = *(const bf16x8*)(Bs + ((size_t)(wn * 64 + ni * 16 + lr) * 64 + kk * 32 + kh * 8) * 2);
#pragma unroll
            for (int mi = 0; mi < 4; ++mi)
#pragma unroll
                for (int ni = 0; ni < 4; ++ni)
                    acc[mi][ni] = __builtin_amdgcn_mfma_f32_16x16x32_bf16(af[mi], bfr[ni], acc[mi][ni], 0, 0, 0);
        }
        __syncthreads();
    }

    // epilogue: C/D layout col=lane&15, row=(lane>>4)*4+reg (m89-verified)
#pragma unroll
    for (int mi = 0; mi < 4; ++mi) {
#pragma unroll
        for (int ni = 0; ni < 4; ++ni) {
            int col = col0 + wn * 64 + ni * 16 + lr;
            float bv = 0.f;
            if constexpr (HASBIAS) bv = bias[col];
#pragma unroll
            for (int r = 0; r < 4; ++r) {
                int row = row0 + wm * 64 + mi * 16 + kh * 4 + r;
                float v = acc[mi][ni][r] + bv;
                if constexpr (RELU) v = fmaxf(v, 0.f);
                store_c(C, (size_t)row * N + col, v);
            }
        }
    }
}

// ---------------- flash attention ----------------
// grid (S/64, H, B), 256 thr = 4 waves, each wave owns 16 q-rows.
// Q/K/V are [B*S, 1024] bf16, head h at col h*64.
__device__ __forceinline__ void stage_tile64(const char* gbase, char* lds, int wave, int lane) {
    // 64 rows x 128B = 8KB = 8 x 1KB, 2 per wave; global row stride = 2048 B
#pragma unroll
    for (int j = 0; j < 2; ++j) {
        int ob   = (wave * 2 + j) * 1024 + lane * 16;
        int row  = ob >> 7;
        int colb = ob & 127;
        const char* gp = gbase + (size_t)row * 2048 + colb;
        char* lp = lds + (wave * 2 + j) * 1024;
        gload_lds16(gp, lp);
    }
}

__global__ __launch_bounds__(256)
void attn_kernel(const u16* __restrict__ Q, const u16* __restrict__ Kt,
                 const u16* __restrict__ V, u16* __restrict__ Ob) {
    __shared__ u16 Ks[64 * 64];
    __shared__ u16 Vs[64 * 64];
    __shared__ u16 Ps[4][16][64];

    const int tid  = threadIdx.x;
    const int lane = tid & 63, wave = tid >> 6;
    const int lr   = lane & 15, kh = lane >> 4;
    const int q0   = blockIdx.x * 64;
    const int h    = blockIdx.y;
    const int b    = blockIdx.z;

    // Q fragments (A-operand): lane holds row lr (local), k = kk*32 + kh*8 + j
    const size_t qrow = (size_t)(b * S_LEN + q0 + wave * 16 + lr);
    bf16x8 qf[2];
    qf[0] = *(const bf16x8*)(Q + qrow * E_DIM + h * HD + 0 * 32 + kh * 8);
    qf[1] = *(const bf16x8*)(Q + qrow * E_DIM + h * HD + 1 * 32 + kh * 8);

    f32x4 o[4];
#pragma unroll
    for (int ni = 0; ni < 4; ++ni) o[ni] = (f32x4){0.f, 0.f, 0.f, 0.f};
    float m_run[4] = {-1e30f, -1e30f, -1e30f, -1e30f};
    float l_run[4] = {0.f, 0.f, 0.f, 0.f};

    for (int kv0 = 0; kv0 < S_LEN; kv0 += 64) {
        const char* kb = (const char*)(Kt + ((size_t)(b * S_LEN + kv0) * E_DIM + h * HD));
        const char* vb = (const char*)(V  + ((size_t)(b * S_LEN + kv0) * E_DIM + h * HD));
        stage_tile64(kb, (char*)Ks, wave, lane);
        stage_tile64(vb, (char*)Vs, wave, lane);
        __syncthreads();

        // S = Q K^T * 0.125 ; wave computes rows wave*16.., all 64 kv cols
        f32x4 s[4];
#pragma unroll
        for (int ni = 0; ni < 4; ++ni) s[ni] = (f32x4){0.f, 0.f, 0.f, 0.f};
#pragma unroll
        for (int ni = 0; ni < 4; ++ni)
#pragma unroll
            for (int kk = 0; kk < 2; ++kk) {
                bf16x8 kf = *(const bf16x8*)(Ks + (size_t)(ni * 16 + lr) * 64 + kk * 32 + kh * 8);
                s[ni] = __builtin_amdgcn_mfma_f32_16x16x32_bf16(qf[kk], kf, s[ni], 0, 0, 0);
            }
#pragma unroll
        for (int ni = 0; ni < 4; ++ni)
#pragma unroll
            for (int r = 0; r < 4; ++r) s[ni][r] *= 0.125f;

        // online softmax: row = kh*4 + r, spread across 16 lanes (lr = col)
        float rm[4];
#pragma unroll
        for (int r = 0; r < 4; ++r) {
            rm[r] = fmaxf(fmaxf(s[0][r], s[1][r]), fmaxf(s[2][r], s[3][r]));
#pragma unroll
            for (int m = 1; m < 16; m <<= 1) rm[r] = fmaxf(rm[r], __shfl_xor(rm[r], m));
        }
        float alpha[4];
#pragma unroll
        for (int r = 0; r < 4; ++r) {
            float mn = fmaxf(m_run[r], rm[r]);
            alpha[r] = __expf(m_run[r] - mn);
            m_run[r] = mn;
        }
        float rs[4] = {0.f, 0.f, 0.f, 0.f};
#pragma unroll
        for (int ni = 0; ni < 4; ++ni)
#pragma unroll
            for (int r = 0; r < 4; ++r) {
                float p = __expf(s[ni][r] - m_run[r]);
                s[ni][r] = p;
                rs[r] += p;
            }
#pragma unroll
        for (int r = 0; r < 4; ++r) {
#pragma unroll
            for (int m = 1; m < 16; m <<= 1) rs[r] += __shfl_xor(rs[r], m);
            l_run[r] = l_run[r] * alpha[r] + rs[r];
        }
#pragma unroll
        for (int ni = 0; ni < 4; ++ni)
#pragma unroll
            for (int r = 0; r < 4; ++r) o[ni][r] *= alpha[r];

        // P (bf16) to LDS in A-fragment layout source
#pragma unroll
        for (int ni = 0; ni < 4; ++ni)
#pragma unroll
            for (int r = 0; r < 4; ++r)
                Ps[wave][kh * 4 + r][ni * 16 + lr] = f2b(s[ni][r]);
        __syncthreads();

        // O += P @ V
#pragma unroll
        for (int kk2 = 0; kk2 < 2; ++kk2) {
            bf16x8 pa = *(const bf16x8*)(&Ps[wave][lr][kk2 * 32 + kh * 8]);
#pragma unroll
            for (int ni = 0; ni < 4; ++ni) {
                u16x8 tmp;
#pragma unroll
                for (int j = 0; j < 8; ++j)
                    tmp[j] = Vs[(size_t)(kk2 * 32 + kh * 8 + j) * 64 + ni * 16 + lr];
                bf16x8 vf = __builtin_bit_cast(bf16x8, tmp);
                o[ni] = __builtin_amdgcn_mfma_f32_16x16x32_bf16(pa, vf, o[ni], 0, 0, 0);
            }
        }
        __syncthreads();   // protect Ks/Vs before next stage
    }

    // normalize + store to [B*S, E] at col h*64
#pragma unroll
    for (int ni = 0; ni < 4; ++ni)
#pragma unroll
        for (int r = 0; r < 4; ++r) {
            float v = o[ni][r] / l_run[r];
            size_t row = (size_t)(b * S_LEN + q0 + wave * 16 + kh * 4 + r);
            Ob[row * E_DIM + h * HD + ni * 16 + lr] = f2b(v);
        }
}

// ---------------- fused residual add + LayerNorm ----------------
// one block per row (E=1024, 256 thr x 4 floats)
__global__ __launch_bounds__(256)
void add_ln(const float* __restrict__ xa, const float* __restrict__ xb2,
            const float* __restrict__ g, const float* __restrict__ be,
            float* __restrict__ of, u16* __restrict__ ob) {
    const int row = blockIdx.x;
    const int t = threadIdx.x;
    const int lane = t & 63, wave = t >> 6;

    float4 va = reinterpret_cast<const float4*>(xa + (size_t)row * E_DIM)[t];
    float4 vb = reinterpret_cast<const float4*>(xb2 + (size_t)row * E_DIM)[t];
    float v0 = va.x + vb.x, v1 = va.y + vb.y, v2 = va.z + vb.z, v3 = va.w + vb.w;
    float s  = v0 + v1 + v2 + v3;
    float s2 = v0 * v0 + v1 * v1 + v2 * v2 + v3 * v3;
#pragma unroll
    for (int m = 32; m >= 1; m >>= 1) {
        s  += __shfl_xor(s, m);
        s2 += __shfl_xor(s2, m);
    }
    __shared__ float red[8];
    if (lane == 0) { red[wave] = s; red[4 + wave] = s2; }
    __syncthreads();
    s  = red[0] + red[1] + red[2] + red[3];
    s2 = red[4] + red[5] + red[6] + red[7];

    float mu   = s * (1.0f / E_DIM);
    float var  = s2 * (1.0f / E_DIM) - mu * mu;
    float rstd = rsqrtf(var + 1e-5f);

    float4 gg = reinterpret_cast<const float4*>(g)[t];
    float4 bb = reinterpret_cast<const float4*>(be)[t];
    float y0 = (v0 - mu) * rstd * gg.x + bb.x;
    float y1 = (v1 - mu) * rstd * gg.y + bb.y;
    float y2 = (v2 - mu) * rstd * gg.z + bb.z;
    float y3 = (v3 - mu) * rstd * gg.w + bb.w;
    if (of) {
        float4 o; o.x = y0; o.y = y1; o.z = y2; o.w = y3;
        reinterpret_cast<float4*>(of + (size_t)row * E_DIM)[t] = o;
    }
    if (ob) {
        ushort4 o;
        o.x = f2b(y0); o.y = f2b(y1); o.z = f2b(y2); o.w = f2b(y3);
        reinterpret_cast<ushort4*>(ob + (size_t)row * E_DIM)[t] = o;
    }
}

// ---------------- launch ----------------
extern "C" void kernel_launch(void* const* d_in, const int* in_sizes, int n_in,
                              void* d_out, int out_size, void* d_ws, size_t ws_size,
                              hipStream_t stream) {
    const float* x   = (const float*)d_in[0];
    const float* Wq  = (const float*)d_in[1];
    const float* Wk  = (const float*)d_in[2];
    const float* Wv  = (const float*)d_in[3];
    const float* Wo  = (const float*)d_in[4];
    const float* g1  = (const float*)d_in[5];
    const float* b1  = (const float*)d_in[6];
    const float* g2  = (const float*)d_in[7];
    const float* b2  = (const float*)d_in[8];
    const float* W1  = (const float*)d_in[9];
    const float* bb1 = (const float*)d_in[10];
    const float* W2  = (const float*)d_in[11];
    const float* bb2 = (const float*)d_in[12];
    float* out = (float*)d_out;

    char* ws = (char*)d_ws;
    const size_t MB = 1024ull * 1024ull;
    // layout (peak 184 MB, with reuse):
    u16* wqb   = (u16*)(ws + 0 * MB);
    u16* wkb   = (u16*)(ws + 2 * MB);
    u16* wvb   = (u16*)(ws + 4 * MB);
    u16* wob   = (u16*)(ws + 6 * MB);
    u16* w1b   = (u16*)(ws + 8 * MB);
    u16* w2b   = (u16*)(ws + 16 * MB);
    u16* xb    = (u16*)(ws + 24 * MB);   // dead after QKV
    u16* Qb    = (u16*)(ws + 40 * MB);   // dead after attn
    u16* Kb    = (u16*)(ws + 56 * MB);
    u16* Vb    = (u16*)(ws + 72 * MB);
    u16* attnb = (u16*)(ws + 88 * MB);   // dead after Wo gemm
    float* attno = (float*)(ws + 104 * MB);  // dead after LN1
    float* hbuf  = (float*)(ws + 136 * MB);
    u16* hb    = (u16*)(ws + 168 * MB);
    u16* ffn1  = (u16*)(ws + 24 * MB);   // reuse xb/Q/K/V region (64MB)
    float* y2  = (float*)(ws + 104 * MB); // reuse attno region

    dim3 blk(256);
    auto cgrid = [](int n4) { int b = (n4 + 255) / 256; return dim3(b > 2048 ? 2048 : b); };

    cast_f32_bf16<<<cgrid(M_ROWS * E_DIM / 4), blk, 0, stream>>>(x, xb, M_ROWS * E_DIM / 4);
    cast_f32_bf16<<<cgrid(E_DIM * E_DIM / 4), blk, 0, stream>>>(Wq, wqb, E_DIM * E_DIM / 4);
    cast_f32_bf16<<<cgrid(E_DIM * E_DIM / 4), blk, 0, stream>>>(Wk, wkb, E_DIM * E_DIM / 4);
    cast_f32_bf16<<<cgrid(E_DIM * E_DIM / 4), blk, 0, stream>>>(Wv, wvb, E_DIM * E_DIM / 4);
    cast_f32_bf16<<<cgrid(E_DIM * E_DIM / 4), blk, 0, stream>>>(Wo, wob, E_DIM * E_DIM / 4);
    cast_f32_bf16<<<cgrid(F_DIM * E_DIM / 4), blk, 0, stream>>>(W1, w1b, F_DIM * E_DIM / 4);
    cast_f32_bf16<<<cgrid(E_DIM * F_DIM / 4), blk, 0, stream>>>(W2, w2b, E_DIM * F_DIM / 4);

    dim3 gEE(E_DIM / 128, M_ROWS / 128);
    gemm_bt<u16, false, false><<<gEE, blk, 0, stream>>>(xb, wqb, Qb, nullptr, M_ROWS, E_DIM, E_DIM);
    gemm_bt<u16, false, false><<<gEE, blk, 0, stream>>>(xb, wkb, Kb, nullptr, M_ROWS, E_DIM, E_DIM);
    gemm_bt<u16, false, false><<<gEE, blk, 0, stream>>>(xb, wvb, Vb, nullptr, M_ROWS, E_DIM, E_DIM);

    attn_kernel<<<dim3(S_LEN / 64, H_NUM, B_NUM), blk, 0, stream>>>(Qb, Kb, Vb, attnb);

    gemm_bt<float, false, false><<<gEE, blk, 0, stream>>>(attnb, wob, attno, nullptr, M_ROWS, E_DIM, E_DIM);

    add_ln<<<dim3(M_ROWS), blk, 0, stream>>>(x, attno, g1, b1, hbuf, hb);

    gemm_bt<u16, true, true><<<dim3(F_DIM / 128, M_ROWS / 128), blk, 0, stream>>>(hb, w1b, ffn1, bb1, M_ROWS, F_DIM, E_DIM);
    gemm_bt<float, false, true><<<gEE, blk, 0, stream>>>(ffn1, w2b, y2, bb2, M_ROWS, E_DIM, F_DIM);

    add_ln<<<dim3(M_ROWS), blk, 0, stream>>>(hbuf, y2, g2, b2, out, nullptr);
}

// Round 2
// 612.963 us; speedup vs baseline: 1.1781x; 1.1781x over previous
//
#include <hip/hip_runtime.h>
#include <stdint.h>

// ---------------- problem constants ----------------
#define E_DIM   1024
#define H_NUM   16
#define HD      64        // head dim
#define F_DIM   4096
#define B_NUM   4
#define S_LEN   2048
#define M_ROWS  (B_NUM * S_LEN)   // 8192

typedef unsigned short u16;
typedef __bf16 bf16_t;
typedef bf16_t  bf16x8 __attribute__((ext_vector_type(8)));
typedef u16     u16x8  __attribute__((ext_vector_type(8)));
typedef float   f32x4  __attribute__((ext_vector_type(4)));

#define AS1 __attribute__((address_space(1)))
#define AS3 __attribute__((address_space(3)))

// async global->LDS, 16B per lane, wave-uniform LDS base + lane*16
__device__ __forceinline__ void gload_lds16(const void* g, void* l) {
    __builtin_amdgcn_global_load_lds((AS1 void*)g, (AS3 void*)l, 16, 0, 0);
}

// f32 -> bf16 RNE
__device__ __forceinline__ u16 f2b(float f) {
    union { float f; unsigned u; } a; a.f = f;
    unsigned u = a.u + 0x7fffu + ((a.u >> 16) & 1u);
    return (u16)(u >> 16);
}

// XOR swizzle for 64-row x 128B LDS tiles: kills the stride-128 bank alias
// for both row-groups-of-8 and row-bit-3 (rows 0..15 all land distinct).
__device__ __forceinline__ int swz_c(int row) {
    return ((row & 7) << 4) ^ ((row & 8) << 2);
}
__device__ __forceinline__ int swz_off(int row, int colb) {
    return (row << 7) + (colb ^ swz_c(row));
}

// ---------------- cast kernel ----------------
__global__ __launch_bounds__(256) void cast_f32_bf16(const float* __restrict__ in,
                                                     u16* __restrict__ out, int n4) {
    int stride = gridDim.x * blockDim.x;
    for (int i = blockIdx.x * blockDim.x + threadIdx.x; i < n4; i += stride) {
        float4 v = reinterpret_cast<const float4*>(in)[i];
        ushort4 o;
        o.x = f2b(v.x); o.y = f2b(v.y); o.z = f2b(v.z); o.w = f2b(v.w);
        reinterpret_cast<ushort4*>(out)[i] = o;
    }
}

// ---------------- GEMM: C[M,N] = A[M,K] * B[N,K]^T ----------------
// 128x128 tile, BK=64, 256 threads (4 waves as 2x2, each 64x64 output).
__device__ __forceinline__ void stage_tile128(const char* gbase, int ldk_elems,
                                              char* lds, int wave, int lane) {
#pragma unroll
    for (int j = 0; j < 4; ++j) {
        int ob   = (wave * 4 + j) * 1024 + lane * 16;
        int row  = ob >> 7;
        int colb = ob & 127;
        const char* gp = gbase + (size_t)row * ((size_t)ldk_elems * 2) + colb;
        char* lp = lds + (wave * 4 + j) * 1024;
        gload_lds16(gp, lp);
    }
}

__device__ __forceinline__ void store_c(float* C, size_t idx, float v) { C[idx] = v; }
__device__ __forceinline__ void store_c(u16* C, size_t idx, float v)   { C[idx] = f2b(v); }

template <typename OutT, bool RELU, bool HASBIAS>
__global__ __launch_bounds__(256)
void gemm_bt(const u16* __restrict__ A, const u16* __restrict__ B,
             OutT* __restrict__ C, const float* __restrict__ bias,
             int M, int N, int K) {
    __shared__ char As[128 * 64 * 2];
    __shared__ char Bs[128 * 64 * 2];
    const int tid  = threadIdx.x;
    const int lane = tid & 63, wave = tid >> 6;
    const int lr   = lane & 15, kh = lane >> 4;
    const int row0 = blockIdx.y * 128, col0 = blockIdx.x * 128;
    const int wm   = wave >> 1, wn = wave & 1;

    f32x4 acc[4][4];
#pragma unroll
    for (int mi = 0; mi < 4; ++mi)
#pragma unroll
        for (int ni = 0; ni < 4; ++ni) acc[mi][ni] = (f32x4){0.f, 0.f, 0.f, 0.f};

    for (int kt = 0; kt < K; kt += 64) {
        stage_tile128((const char*)(A + (size_t)row0 * K + kt), K, As, wave, lane);
        stage_tile128((const char*)(B + (size_t)col0 * K + kt), K, Bs, wave, lane);
        __syncthreads();
#pragma unroll
        for (int kk = 0; kk < 2; ++kk) {
            bf16x8 af[4], bfr[4];
#pragma unroll
            for (int mi = 0; mi < 4; ++mi)
                af[mi] = *(const bf16x8*)(As + ((size_t)(wm * 64 + mi * 16 + lr) * 64 + kk * 32 + kh * 8) * 2);
#pragma unroll
            for (int ni = 0; ni < 4; ++ni)
                bfr[ni] = *(const bf16x8*)(Bs + ((size_t)(wn * 64 + ni * 16 + lr) * 64 + kk * 32 + kh * 8) * 2);
#pragma unroll
            for (int mi = 0; mi < 4; ++mi)
#pragma unroll
                for (int ni = 0; ni < 4; ++ni)
                    acc[mi][ni] = __builtin_amdgcn_mfma_f32_16x16x32_bf16(af[mi], bfr[ni], acc[mi][ni], 0, 0, 0);
        }
        __syncthreads();
    }

#pragma unroll
    for (int mi = 0; mi < 4; ++mi) {
#pragma unroll
        for (int ni = 0; ni < 4; ++ni) {
            int col = col0 + wn * 64 + ni * 16 + lr;
            float bv = 0.f;
            if constexpr (HASBIAS) bv = bias[col];
#pragma unroll
            for (int r = 0; r < 4; ++r) {
                int row = row0 + wm * 64 + mi * 16 + kh * 4 + r;
                float v = acc[mi][ni][r] + bv;
                if constexpr (RELU) v = fmaxf(v, 0.f);
                store_c(C, (size_t)row * N + col, v);
            }
        }
    }
}

// ---------------- flash attention ----------------
// grid (S/64, H, B), 256 thr = 4 waves, each wave owns 16 q-rows.
// Q/K/V are [B*S, 1024] bf16, head h at col h*64.
// K tile: swizzled via pre-swizzled global source + linear global_load_lds.
// V tile: reg-staged and written TRANSPOSED (Vt[d][kv]) + swizzled, so PV's
// B-fragments are vector ds_read_b128 instead of 64 scalar reads.
__global__ __launch_bounds__(256)
void attn_kernel(const u16* __restrict__ Q, const u16* __restrict__ Kt,
                 const u16* __restrict__ V, u16* __restrict__ Ob) {
    __shared__ char Ks[64 * 128];          // [kv][d]   swizzled
    __shared__ char Vt[64 * 128];          // [d][kv]   swizzled (transposed)
    __shared__ char Ps[4 * 16 * 128];      // per-wave [qrow][kv] swizzled

    const int tid  = threadIdx.x;
    const int lane = tid & 63, wave = tid >> 6;
    const int lr   = lane & 15, kh = lane >> 4;
    const int q0   = blockIdx.x * 64;
    const int h    = blockIdx.y;
    const int b    = blockIdx.z;

    // Q fragments (A-operand), pre-scaled by 1/sqrt(hd)=0.125 (exact in bf16)
    const size_t qrow = (size_t)(b * S_LEN + q0 + wave * 16 + lr);
    bf16x8 qf[2];
    qf[0] = *(const bf16x8*)(Q + qrow * E_DIM + h * HD + 0 * 32 + kh * 8);
    qf[1] = *(const bf16x8*)(Q + qrow * E_DIM + h * HD + 1 * 32 + kh * 8);
#pragma unroll
    for (int kk = 0; kk < 2; ++kk)
#pragma unroll
        for (int j = 0; j < 8; ++j)
            qf[kk][j] = (bf16_t)((float)qf[kk][j] * 0.125f);

    f32x4 o[4];
#pragma unroll
    for (int ni = 0; ni < 4; ++ni) o[ni] = (f32x4){0.f, 0.f, 0.f, 0.f};
    float m_run[4] = {-1e30f, -1e30f, -1e30f, -1e30f};
    float l_run[4] = {0.f, 0.f, 0.f, 0.f};

    for (int kv0 = 0; kv0 < S_LEN; kv0 += 64) {
        __syncthreads();   // previous tile fully consumed; Ks/Vt reusable

        // V -> regs (lane = kv row, this wave covers d = wave*16..+15)
        const u16* vp = V + (size_t)(b * S_LEN + kv0 + lane) * E_DIM + h * HD + wave * 16;
        bf16x8 va = *(const bf16x8*)(vp);
        bf16x8 vb = *(const bf16x8*)(vp + 8);

        // K -> LDS via global_load_lds with pre-swizzled source (rule 21)
        const char* kb = (const char*)(Kt + ((size_t)(b * S_LEN + kv0) * E_DIM + h * HD));
#pragma unroll
        for (int j = 0; j < 2; ++j) {
            int ob   = (wave * 2 + j) * 1024 + lane * 16;
            int row  = ob >> 7;
            int colb = (ob & 127) ^ swz_c(row);
            gload_lds16(kb + (size_t)row * 2048 + colb, Ks + (wave * 2 + j) * 1024);
        }

        // V regs -> Vt transposed + swizzled (conflict-free scatter writes)
        u16x8 vau = __builtin_bit_cast(u16x8, va);
        u16x8 vbu = __builtin_bit_cast(u16x8, vb);
#pragma unroll
        for (int jj = 0; jj < 8; ++jj) {
            int d0 = wave * 16 + jj;
            int d1 = wave * 16 + 8 + jj;
            *(u16*)(Vt + (d0 << 7) + ((lane * 2) ^ swz_c(d0))) = vau[jj];
            *(u16*)(Vt + (d1 << 7) + ((lane * 2) ^ swz_c(d1))) = vbu[jj];
        }

        __syncthreads();   // staging visible (barrier drains vmcnt/lgkmcnt)

        // S = (Q*0.125) K^T : wave computes rows wave*16.., all 64 kv cols
        f32x4 s[4];
#pragma unroll
        for (int ni = 0; ni < 4; ++ni) s[ni] = (f32x4){0.f, 0.f, 0.f, 0.f};
#pragma unroll
        for (int ni = 0; ni < 4; ++ni)
#pragma unroll
            for (int kk = 0; kk < 2; ++kk) {
                bf16x8 kf = *(const bf16x8*)(Ks + swz_off(ni * 16 + lr, (kk * 32 + kh * 8) * 2));
                s[ni] = __builtin_amdgcn_mfma_f32_16x16x32_bf16(qf[kk], kf, s[ni], 0, 0, 0);
            }

        // online softmax: row = kh*4 + r, spread across 16 lanes (lr = col)
        float rm[4];
#pragma unroll
        for (int r = 0; r < 4; ++r) {
            rm[r] = fmaxf(fmaxf(s[0][r], s[1][r]), fmaxf(s[2][r], s[3][r]));
#pragma unroll
            for (int m = 1; m < 16; m <<= 1) rm[r] = fmaxf(rm[r], __shfl_xor(rm[r], m));
        }
        float alpha[4];
#pragma unroll
        for (int r = 0; r < 4; ++r) {
            float mn = fmaxf(m_run[r], rm[r]);
            alpha[r] = __expf(m_run[r] - mn);
            m_run[r] = mn;
        }
        float rs[4] = {0.f, 0.f, 0.f, 0.f};
#pragma unroll
        for (int ni = 0; ni < 4; ++ni)
#pragma unroll
            for (int r = 0; r < 4; ++r) {
                float p = __expf(s[ni][r] - m_run[r]);
                s[ni][r] = p;
                rs[r] += p;
            }
#pragma unroll
        for (int r = 0; r < 4; ++r) {
#pragma unroll
            for (int m = 1; m < 16; m <<= 1) rs[r] += __shfl_xor(rs[r], m);
            l_run[r] = l_run[r] * alpha[r] + rs[r];
        }
#pragma unroll
        for (int ni = 0; ni < 4; ++ni)
#pragma unroll
            for (int r = 0; r < 4; ++r) o[ni][r] *= alpha[r];

        // P (bf16) to LDS (wave-private, swizzled; no barrier needed)
#pragma unroll
        for (int ni = 0; ni < 4; ++ni)
#pragma unroll
            for (int r = 0; r < 4; ++r) {
                int rr = kh * 4 + r;
                *(u16*)(Ps + wave * 2048 + swz_off(rr, (ni * 16 + lr) * 2)) = f2b(s[ni][r]);
            }

        // O += P @ V  (all fragments now vector ds_read_b128)
#pragma unroll
        for (int kk2 = 0; kk2 < 2; ++kk2) {
            bf16x8 pa = *(const bf16x8*)(Ps + wave * 2048 + swz_off(lr, (kk2 * 32 + kh * 8) * 2));
#pragma unroll
            for (int ni = 0; ni < 4; ++ni) {
                bf16x8 vf = *(const bf16x8*)(Vt + swz_off(ni * 16 + lr, (kk2 * 32 + kh * 8) * 2));
                o[ni] = __builtin_amdgcn_mfma_f32_16x16x32_bf16(pa, vf, o[ni], 0, 0, 0);
            }
        }
    }

    // normalize + store to [B*S, E] at col h*64
#pragma unroll
    for (int ni = 0; ni < 4; ++ni)
#pragma unroll
        for (int r = 0; r < 4; ++r) {
            float v = o[ni][r] / l_run[r];
            size_t row = (size_t)(b * S_LEN + q0 + wave * 16 + kh * 4 + r);
            Ob[row * E_DIM + h * HD + ni * 16 + lr] = f2b(v);
        }
}

// ---------------- fused residual add + LayerNorm ----------------
__global__ __launch_bounds__(256)
void add_ln(const float* __restrict__ xa, const float* __restrict__ xb2,
            const float* __restrict__ g, const float* __restrict__ be,
            float* __restrict__ of, u16* __restrict__ ob) {
    const int row = blockIdx.x;
    const int t = threadIdx.x;
    const int lane = t & 63, wave = t >> 6;

    float4 va = reinterpret_cast<const float4*>(xa + (size_t)row * E_DIM)[t];
    float4 vb = reinterpret_cast<const float4*>(xb2 + (size_t)row * E_DIM)[t];
    float v0 = va.x + vb.x, v1 = va.y + vb.y, v2 = va.z + vb.z, v3 = va.w + vb.w;
    float s  = v0 + v1 + v2 + v3;
    float s2 = v0 * v0 + v1 * v1 + v2 * v2 + v3 * v3;
#pragma unroll
    for (int m = 32; m >= 1; m >>= 1) {
        s  += __shfl_xor(s, m);
        s2 += __shfl_xor(s2, m);
    }
    __shared__ float red[8];
    if (lane == 0) { red[wave] = s; red[4 + wave] = s2; }
    __syncthreads();
    s  = red[0] + red[1] + red[2] + red[3];
    s2 = red[4] + red[5] + red[6] + red[7];

    float mu   = s * (1.0f / E_DIM);
    float var  = s2 * (1.0f / E_DIM) - mu * mu;
    float rstd = rsqrtf(var + 1e-5f);

    float4 gg = reinterpret_cast<const float4*>(g)[t];
    float4 bb = reinterpret_cast<const float4*>(be)[t];
    float y0 = (v0 - mu) * rstd * gg.x + bb.x;
    float y1 = (v1 - mu) * rstd * gg.y + bb.y;
    float y2 = (v2 - mu) * rstd * gg.z + bb.z;
    float y3 = (v3 - mu) * rstd * gg.w + bb.w;
    if (of) {
        float4 o; o.x = y0; o.y = y1; o.z = y2; o.w = y3;
        reinterpret_cast<float4*>(of + (size_t)row * E_DIM)[t] = o;
    }
    if (ob) {
        ushort4 o;
        o.x = f2b(y0); o.y = f2b(y1); o.z = f2b(y2); o.w = f2b(y3);
        reinterpret_cast<ushort4*>(ob + (size_t)row * E_DIM)[t] = o;
    }
}

// ---------------- launch ----------------
extern "C" void kernel_launch(void* const* d_in, const int* in_sizes, int n_in,
                              void* d_out, int out_size, void* d_ws, size_t ws_size,
                              hipStream_t stream) {
    const float* x   = (const float*)d_in[0];
    const float* Wq  = (const float*)d_in[1];
    const float* Wk  = (const float*)d_in[2];
    const float* Wv  = (const float*)d_in[3];
    const float* Wo  = (const float*)d_in[4];
    const float* g1  = (const float*)d_in[5];
    const float* b1  = (const float*)d_in[6];
    const float* g2  = (const float*)d_in[7];
    const float* b2  = (const float*)d_in[8];
    const float* W1  = (const float*)d_in[9];
    const float* bb1 = (const float*)d_in[10];
    const float* W2  = (const float*)d_in[11];
    const float* bb2 = (const float*)d_in[12];
    float* out = (float*)d_out;

    char* ws = (char*)d_ws;
    const size_t MB = 1024ull * 1024ull;
    u16* wqb   = (u16*)(ws + 0 * MB);
    u16* wkb   = (u16*)(ws + 2 * MB);
    u16* wvb   = (u16*)(ws + 4 * MB);
    u16* wob   = (u16*)(ws + 6 * MB);
    u16* w1b   = (u16*)(ws + 8 * MB);
    u16* w2b   = (u16*)(ws + 16 * MB);
    u16* xb    = (u16*)(ws + 24 * MB);
    u16* Qb    = (u16*)(ws + 40 * MB);
    u16* Kb    = (u16*)(ws + 56 * MB);
    u16* Vb    = (u16*)(ws + 72 * MB);
    u16* attnb = (u16*)(ws + 88 * MB);
    float* attno = (float*)(ws + 104 * MB);
    float* hbuf  = (float*)(ws + 136 * MB);
    u16* hb    = (u16*)(ws + 168 * MB);
    u16* ffn1  = (u16*)(ws + 24 * MB);
    float* y2  = (float*)(ws + 104 * MB);

    dim3 blk(256);
    auto cgrid = [](int n4) { int b = (n4 + 255) / 256; return dim3(b > 2048 ? 2048 : b); };

    cast_f32_bf16<<<cgrid(M_ROWS * E_DIM / 4), blk, 0, stream>>>(x, xb, M_ROWS * E_DIM / 4);
    cast_f32_bf16<<<cgrid(E_DIM * E_DIM / 4), blk, 0, stream>>>(Wq, wqb, E_DIM * E_DIM / 4);
    cast_f32_bf16<<<cgrid(E_DIM * E_DIM / 4), blk, 0, stream>>>(Wk, wkb, E_DIM * E_DIM / 4);
    cast_f32_bf16<<<cgrid(E_DIM * E_DIM / 4), blk, 0, stream>>>(Wv, wvb, E_DIM * E_DIM / 4);
    cast_f32_bf16<<<cgrid(E_DIM * E_DIM / 4), blk, 0, stream>>>(Wo, wob, E_DIM * E_DIM / 4);
    cast_f32_bf16<<<cgrid(F_DIM * E_DIM / 4), blk, 0, stream>>>(W1, w1b, F_DIM * E_DIM / 4);
    cast_f32_bf16<<<cgrid(E_DIM * F_DIM / 4), blk, 0, stream>>>(W2, w2b, E_DIM * F_DIM / 4);

    dim3 gEE(E_DIM / 128, M_ROWS / 128);
    gemm_bt<u16, false, false><<<gEE, blk, 0, stream>>>(xb, wqb, Qb, nullptr, M_ROWS, E_DIM, E_DIM);
    gemm_bt<u16, false, false><<<gEE, blk, 0, stream>>>(xb, wkb, Kb, nullptr, M_ROWS, E_DIM, E_DIM);
    gemm_bt<u16, false, false><<<gEE, blk, 0, stream>>>(xb, wvb, Vb, nullptr, M_ROWS, E_DIM, E_DIM);

    attn_kernel<<<dim3(S_LEN / 64, H_NUM, B_NUM), blk, 0, stream>>>(Qb, Kb, Vb, attnb);

    gemm_bt<float, false, false><<<gEE, blk, 0, stream>>>(attnb, wob, attno, nullptr, M_ROWS, E_DIM, E_DIM);

    add_ln<<<dim3(M_ROWS), blk, 0, stream>>>(x, attno, g1, b1, hbuf, hb);

    gemm_bt<u16, true, true><<<dim3(F_DIM / 128, M_ROWS / 128), blk, 0, stream>>>(hb, w1b, ffn1, bb1, M_ROWS, F_DIM, E_DIM);
    gemm_bt<float, false, true><<<gEE, blk, 0, stream>>>(ffn1, w2b, y2, bb2, M_ROWS, E_DIM, F_DIM);

    add_ln<<<dim3(M_ROWS), blk, 0, stream>>>(hbuf, y2, g2, b2, out, nullptr);
}

// Round 3
// 521.213 us; speedup vs baseline: 1.3855x; 1.1760x over previous
//
#include <hip/hip_runtime.h>
#include <stdint.h>

// ---------------- problem constants ----------------
#define E_DIM   1024
#define H_NUM   16
#define HD      64        // head dim
#define F_DIM   4096
#define B_NUM   4
#define S_LEN   2048
#define M_ROWS  (B_NUM * S_LEN)   // 8192

typedef unsigned short u16;
typedef __bf16 bf16_t;
typedef bf16_t  bf16x8 __attribute__((ext_vector_type(8)));
typedef u16     u16x8  __attribute__((ext_vector_type(8)));
typedef float   f32x4  __attribute__((ext_vector_type(4)));
typedef float   f32x16 __attribute__((ext_vector_type(16)));
typedef unsigned u32x4 __attribute__((ext_vector_type(4)));

#define AS1 __attribute__((address_space(1)))
#define AS3 __attribute__((address_space(3)))

// async global->LDS, 16B per lane, wave-uniform LDS base + lane*16
__device__ __forceinline__ void gload_lds16(const void* g, void* l) {
    __builtin_amdgcn_global_load_lds((AS1 void*)g, (AS3 void*)l, 16, 0, 0);
}

// f32 -> bf16 RNE
__device__ __forceinline__ u16 f2b(float f) {
    union { float f; unsigned u; } a; a.f = f;
    unsigned u = a.u + 0x7fffu + ((a.u >> 16) & 1u);
    return (u16)(u >> 16);
}

// pack two f32 -> 2xbf16 in one u32 (lo = first arg)
__device__ __forceinline__ unsigned cvt_pk_bf16(float lo, float hi) {
    unsigned r;
    asm("v_cvt_pk_bf16_f32 %0, %1, %2" : "=v"(r) : "v"(lo), "v"(hi));
    return r;
}

// XOR swizzle for 32-row x 128B LDS tiles (K tile)
__device__ __forceinline__ int swz_c(int row) {
    return ((row & 7) << 4) ^ ((row & 8) << 2);
}
// XOR swizzle for 64-row x 64B LDS tiles (Vt tile): 2-bit slot from d>>1
__device__ __forceinline__ int swz_v(int row) {
    return ((row >> 1) & 3) << 4;
}

// ---------------- cast kernel ----------------
__global__ __launch_bounds__(256) void cast_f32_bf16(const float* __restrict__ in,
                                                     u16* __restrict__ out, int n4) {
    int stride = gridDim.x * blockDim.x;
    for (int i = blockIdx.x * blockDim.x + threadIdx.x; i < n4; i += stride) {
        float4 v = reinterpret_cast<const float4*>(in)[i];
        ushort4 o;
        o.x = f2b(v.x); o.y = f2b(v.y); o.z = f2b(v.z); o.w = f2b(v.w);
        reinterpret_cast<ushort4*>(out)[i] = o;
    }
}

// ---------------- GEMM: C[M,N] = A[M,K] * B[N,K]^T ---------------- (unchanged)
__device__ __forceinline__ void stage_tile128(const char* gbase, int ldk_elems,
                                              char* lds, int wave, int lane) {
#pragma unroll
    for (int j = 0; j < 4; ++j) {
        int ob   = (wave * 4 + j) * 1024 + lane * 16;
        int row  = ob >> 7;
        int colb = ob & 127;
        const char* gp = gbase + (size_t)row * ((size_t)ldk_elems * 2) + colb;
        char* lp = lds + (wave * 4 + j) * 1024;
        gload_lds16(gp, lp);
    }
}

__device__ __forceinline__ void store_c(float* C, size_t idx, float v) { C[idx] = v; }
__device__ __forceinline__ void store_c(u16* C, size_t idx, float v)   { C[idx] = f2b(v); }

template <typename OutT, bool RELU, bool HASBIAS>
__global__ __launch_bounds__(256)
void gemm_bt(const u16* __restrict__ A, const u16* __restrict__ B,
             OutT* __restrict__ C, const float* __restrict__ bias,
             int M, int N, int K) {
    __shared__ char As[128 * 64 * 2];
    __shared__ char Bs[128 * 64 * 2];
    const int tid  = threadIdx.x;
    const int lane = tid & 63, wave = tid >> 6;
    const int lr   = lane & 15, kh = lane >> 4;
    const int row0 = blockIdx.y * 128, col0 = blockIdx.x * 128;
    const int wm   = wave >> 1, wn = wave & 1;

    f32x4 acc[4][4];
#pragma unroll
    for (int mi = 0; mi < 4; ++mi)
#pragma unroll
        for (int ni = 0; ni < 4; ++ni) acc[mi][ni] = (f32x4){0.f, 0.f, 0.f, 0.f};

    for (int kt = 0; kt < K; kt += 64) {
        stage_tile128((const char*)(A + (size_t)row0 * K + kt), K, As, wave, lane);
        stage_tile128((const char*)(B + (size_t)col0 * K + kt), K, Bs, wave, lane);
        __syncthreads();
#pragma unroll
        for (int kk = 0; kk < 2; ++kk) {
            bf16x8 af[4], bfr[4];
#pragma unroll
            for (int mi = 0; mi < 4; ++mi)
                af[mi] = *(const bf16x8*)(As + ((size_t)(wm * 64 + mi * 16 + lr) * 64 + kk * 32 + kh * 8) * 2);
#pragma unroll
            for (int ni = 0; ni < 4; ++ni)
                bfr[ni] = *(const bf16x8*)(Bs + ((size_t)(wn * 64 + ni * 16 + lr) * 64 + kk * 32 + kh * 8) * 2);
#pragma unroll
            for (int mi = 0; mi < 4; ++mi)
#pragma unroll
                for (int ni = 0; ni < 4; ++ni)
                    acc[mi][ni] = __builtin_amdgcn_mfma_f32_16x16x32_bf16(af[mi], bfr[ni], acc[mi][ni], 0, 0, 0);
        }
        __syncthreads();
    }

#pragma unroll
    for (int mi = 0; mi < 4; ++mi) {
#pragma unroll
        for (int ni = 0; ni < 4; ++ni) {
            int col = col0 + wn * 64 + ni * 16 + lr;
            float bv = 0.f;
            if constexpr (HASBIAS) bv = bias[col];
#pragma unroll
            for (int r = 0; r < 4; ++r) {
                int row = row0 + wm * 64 + mi * 16 + kh * 4 + r;
                float v = acc[mi][ni][r] + bv;
                if constexpr (RELU) v = fmaxf(v, 0.f);
                store_c(C, (size_t)row * N + col, v);
            }
        }
    }
}

// ---------------- flash attention, 32x32 swapped-QK structure ----------------
// grid (S/128, H, B), 256 thr = 4 waves, each wave owns 32 q-rows.
// S^T = mfma(K, Q): each lane owns q-col = lane&31 -> softmax is lane-local
// (+1 shfl_xor(32) pair-combine).  P packed in-register (cvt_pk + shfl) to
// the PV B-fragment.  O^T = mfma(V^T, P^T) keeps the q index lane-local for
// alpha rescale.  KVBLK=32, double-buffered K/Vt, one barrier per iter.
#define KVBLK 32
#define SC_LOG2E 0.1803368801111204f   // 0.125 * log2(e)

__global__ __launch_bounds__(256, 4)
void attn_kernel(const u16* __restrict__ Q, const u16* __restrict__ Kt,
                 const u16* __restrict__ V, u16* __restrict__ Ob) {
    __shared__ char Ks[2][KVBLK * 128];   // [kv][d] swizzled, 4KB each
    __shared__ char Vt[2][64 * 64];       // [d][kv] swizzled, 4KB each

    const int tid  = threadIdx.x;
    const int lane = tid & 63, wave = tid >> 6;
    const int l31  = lane & 31, hi = lane >> 5;
    const int q0   = blockIdx.x * 128;
    const int h    = blockIdx.y;
    const int b    = blockIdx.z;

    // ---- Q fragments: lane holds its q-row, the hi*8 half of each 16-d chunk
    const size_t qrow = (size_t)(b * S_LEN + q0 + wave * 32 + l31);
    bf16x8 qf[4];
#pragma unroll
    for (int c = 0; c < 4; ++c)
        qf[c] = *(const bf16x8*)(Q + qrow * E_DIM + h * HD + c * 16 + hi * 8);

    f32x16 o0 = {}, o1 = {};
    float m_run = -1e30f, l_run = 0.f;

    const u16* Vg = V + (size_t)(b * S_LEN) * E_DIM + h * HD;
    const char* Kg = (const char*)(Kt + (size_t)(b * S_LEN) * E_DIM + h * HD);

    // K staging: wave w covers rows w*8..w*8+7 of the 32-row tile
    const int krow  = wave * 8 + (lane >> 3);
    const int kcolb = ((lane & 7) * 16) ^ swz_c(krow);

    u16 vst[8];
    // ---- prologue: stage tile 0
    gload_lds16(Kg + (size_t)krow * 2048 + kcolb, Ks[0] + wave * 1024);
    {
        const u16* vp = Vg + (size_t)(wave * 8) * E_DIM + lane;
#pragma unroll
        for (int i = 0; i < 8; ++i) vst[i] = vp[(size_t)i * E_DIM];
        u16x8 vv;
#pragma unroll
        for (int i = 0; i < 8; ++i) vv[i] = vst[i];
        *(u16x8*)(Vt[0] + lane * 64 + ((wave * 16) ^ swz_v(lane))) = vv;
    }
    __syncthreads();

    const int NT = S_LEN / KVBLK;   // 64
    for (int t = 0; t < NT; ++t) {
        const int cur = t & 1;
        // ---- prefetch next tile
        if (t < NT - 1) {
            const int kv0n = (t + 1) * KVBLK;
            gload_lds16(Kg + (size_t)(kv0n + krow) * 2048 + kcolb, Ks[cur ^ 1] + wave * 1024);
            const u16* vp = Vg + (size_t)(kv0n + wave * 8) * E_DIM + lane;
#pragma unroll
            for (int i = 0; i < 8; ++i) vst[i] = vp[(size_t)i * E_DIM];
        }

        // ---- S^T = K Q^T (scaled later): 4 MFMAs over d-chunks
        f32x16 st = {};
#pragma unroll
        for (int c = 0; c < 4; ++c) {
            bf16x8 kf = *(const bf16x8*)(Ks[cur] + l31 * 128 + ((c * 32 + hi * 16) ^ swz_c(l31)));
            st = __builtin_amdgcn_mfma_f32_32x32x16_bf16(kf, qf[c], st, 0, 0, 0);
        }

        // ---- online softmax (lane owns q-col; rows kv = (r&3)+8*(r>>2)+4*hi)
        float pm = st[0];
#pragma unroll
        for (int i = 1; i < 16; ++i) pm = fmaxf(pm, st[i]);
        pm = fmaxf(pm, __shfl_xor(pm, 32));
        if (__any(pm > m_run + 64.f)) {     // defer-max: THR=8 in ln-domain
            float mn = fmaxf(m_run, pm);
            float al = exp2f((m_run - mn) * SC_LOG2E);
#pragma unroll
            for (int r = 0; r < 16; ++r) { o0[r] *= al; o1[r] *= al; }
            l_run *= al;
            m_run = mn;
        }
        const float mc = m_run * SC_LOG2E;
        float p[16];
        float rs = 0.f;
#pragma unroll
        for (int i = 0; i < 16; ++i) {
            p[i] = exp2f(__builtin_fmaf(st[i], SC_LOG2E, -mc));
            rs += p[i];
        }
        rs += __shfl_xor(rs, 32);
        l_run += rs;

        // ---- pack P to bf16 pairs, exchange across the hi-split (T12)
        unsigned w[8], x[8];
#pragma unroll
        for (int i = 0; i < 8; ++i) w[i] = cvt_pk_bf16(p[2 * i], p[2 * i + 1]);
#pragma unroll
        for (int i = 0; i < 8; ++i) x[i] = __shfl_xor(w[i], 32);

        // ---- PV: O^T += V^T P^T ; V^T A-frag from Vt, P^T B-frag from regs
#pragma unroll
        for (int cc = 0; cc < 2; ++cc) {
            u32x4 fw;
            fw[0] = hi ? x[4 * cc + 2] : w[4 * cc];
            fw[1] = hi ? x[4 * cc + 3] : w[4 * cc + 1];
            fw[2] = hi ? w[4 * cc + 2] : x[4 * cc];
            fw[3] = hi ? w[4 * cc + 3] : x[4 * cc + 1];
            bf16x8 pf = __builtin_bit_cast(bf16x8, fw);
            bf16x8 v0 = *(const bf16x8*)(Vt[cur] + l31 * 64 + ((cc * 32 + hi * 16) ^ swz_v(l31)));
            bf16x8 v1 = *(const bf16x8*)(Vt[cur] + (32 + l31) * 64 + ((cc * 32 + hi * 16) ^ swz_v(32 + l31)));
            o0 = __builtin_amdgcn_mfma_f32_32x32x16_bf16(v0, pf, o0, 0, 0, 0);
            o1 = __builtin_amdgcn_mfma_f32_32x32x16_bf16(v1, pf, o1, 0, 0, 0);
        }

        // ---- write next Vt (regs -> LDS, different buffer), then barrier
        if (t < NT - 1) {
            u16x8 vv;
#pragma unroll
            for (int i = 0; i < 8; ++i) vv[i] = vst[i];
            *(u16x8*)(Vt[cur ^ 1] + lane * 64 + ((wave * 16) ^ swz_v(lane))) = vv;
        }
        __syncthreads();
    }

    // ---- epilogue: normalize, merge the hi-split halves, 2x dwordx4 store
    const float inv = 1.0f / l_run;
    unsigned m0[16], xx[16];
#pragma unroll
    for (int g = 0; g < 4; ++g)
#pragma unroll
        for (int u = 0; u < 2; ++u) {
            int r = g * 4 + 2 * u;
            m0[2 * g + u]     = cvt_pk_bf16(o0[r] * inv, o0[r + 1] * inv);
            m0[8 + 2 * g + u] = cvt_pk_bf16(o1[r] * inv, o1[r + 1] * inv);
        }
#pragma unroll
    for (int i = 0; i < 16; ++i) xx[i] = __shfl_xor(m0[i], 32);

    u32x4 wa, wb;
#pragma unroll
    for (int g = 0; g < 4; ++g) {
        unsigned e0 = hi ? xx[8 + 2 * g]     : m0[2 * g];
        unsigned e1 = hi ? xx[8 + 2 * g + 1] : m0[2 * g + 1];
        unsigned e2 = hi ? m0[8 + 2 * g]     : xx[2 * g];
        unsigned e3 = hi ? m0[8 + 2 * g + 1] : xx[2 * g + 1];
        if (g < 2) { wa[2 * g] = e0; wa[2 * g + 1] = e1; }
        else       { wb[2 * (g - 2)] = e0; wb[2 * (g - 2) + 1] = e1; }
        // interleave: within each g the four words are d=8g..8g+7
        if (g < 2) { /* placeholder, replaced below */ }
        (void)e2; (void)e3;
    }
    // rebuild properly: per g the word order is e0,e1,e2,e3 = d 8g..8g+7
    {
        unsigned ow[8];
#pragma unroll
        for (int g = 0; g < 4; ++g) {
            ow[2 * g + 0] = hi ? xx[8 + 2 * g]     : m0[2 * g];
            ow[2 * g + 1] = hi ? xx[8 + 2 * g + 1] : m0[2 * g + 1];
        }
        // ow currently holds only the first half of each octet; build full:
        unsigned full[8];
#pragma unroll
        for (int g = 0; g < 4; ++g) {
            full[2 * g + 0] = ow[2 * g + 0];
            full[2 * g + 1] = ow[2 * g + 1];
        }
        unsigned sec[8];
#pragma unroll
        for (int g = 0; g < 4; ++g) {
            sec[2 * g + 0] = hi ? m0[8 + 2 * g]     : xx[2 * g];
            sec[2 * g + 1] = hi ? m0[8 + 2 * g + 1] : xx[2 * g + 1];
        }
        // final layout per g: full[2g], full[2g+1] (d=8g+0..3), sec[2g], sec[2g+1] (d=8g+4..7)
        u32x4 out0, out1;
        out0[0] = full[0]; out0[1] = full[1]; out0[2] = sec[0]; out0[3] = sec[1];
        out1[0] = full[2]; out1[1] = full[3]; out1[2] = sec[2]; out1[3] = sec[3];
        u32x4 out2, out3;
        out2[0] = full[4]; out2[1] = full[5]; out2[2] = sec[4]; out2[3] = sec[5];
        out3[0] = full[6]; out3[1] = full[7]; out3[2] = sec[6]; out3[3] = sec[7];
        u16* op = Ob + qrow * E_DIM + h * HD + hi * 32;
        *(u32x4*)(op)      = out0;
        *(u32x4*)(op + 8)  = out1;
        *(u32x4*)(op + 16) = out2;
        *(u32x4*)(op + 24) = out3;
    }
}

// ---------------- fused residual add + LayerNorm ---------------- (unchanged)
__global__ __launch_bounds__(256)
void add_ln(const float* __restrict__ xa, const float* __restrict__ xb2,
            const float* __restrict__ g, const float* __restrict__ be,
            float* __restrict__ of, u16* __restrict__ ob) {
    const int row = blockIdx.x;
    const int t = threadIdx.x;
    const int lane = t & 63, wave = t >> 6;

    float4 va = reinterpret_cast<const float4*>(xa + (size_t)row * E_DIM)[t];
    float4 vb = reinterpret_cast<const float4*>(xb2 + (size_t)row * E_DIM)[t];
    float v0 = va.x + vb.x, v1 = va.y + vb.y, v2 = va.z + vb.z, v3 = va.w + vb.w;
    float s  = v0 + v1 + v2 + v3;
    float s2 = v0 * v0 + v1 * v1 + v2 * v2 + v3 * v3;
#pragma unroll
    for (int m = 32; m >= 1; m >>= 1) {
        s  += __shfl_xor(s, m);
        s2 += __shfl_xor(s2, m);
    }
    __shared__ float red[8];
    if (lane == 0) { red[wave] = s; red[4 + wave] = s2; }
    __syncthreads();
    s  = red[0] + red[1] + red[2] + red[3];
    s2 = red[4] + red[5] + red[6] + red[7];

    float mu   = s * (1.0f / E_DIM);
    float var  = s2 * (1.0f / E_DIM) - mu * mu;
    float rstd = rsqrtf(var + 1e-5f);

    float4 gg = reinterpret_cast<const float4*>(g)[t];
    float4 bb = reinterpret_cast<const float4*>(be)[t];
    float y0 = (v0 - mu) * rstd * gg.x + bb.x;
    float y1 = (v1 - mu) * rstd * gg.y + bb.y;
    float y2 = (v2 - mu) * rstd * gg.z + bb.z;
    float y3 = (v3 - mu) * rstd * gg.w + bb.w;
    if (of) {
        float4 o; o.x = y0; o.y = y1; o.z = y2; o.w = y3;
        reinterpret_cast<float4*>(of + (size_t)row * E_DIM)[t] = o;
    }
    if (ob) {
        ushort4 o;
        o.x = f2b(y0); o.y = f2b(y1); o.z = f2b(y2); o.w = f2b(y3);
        reinterpret_cast<ushort4*>(ob + (size_t)row * E_DIM)[t] = o;
    }
}

// ---------------- launch ----------------
extern "C" void kernel_launch(void* const* d_in, const int* in_sizes, int n_in,
                              void* d_out, int out_size, void* d_ws, size_t ws_size,
                              hipStream_t stream) {
    const float* x   = (const float*)d_in[0];
    const float* Wq  = (const float*)d_in[1];
    const float* Wk  = (const float*)d_in[2];
    const float* Wv  = (const float*)d_in[3];
    const float* Wo  = (const float*)d_in[4];
    const float* g1  = (const float*)d_in[5];
    const float* b1  = (const float*)d_in[6];
    const float* g2  = (const float*)d_in[7];
    const float* b2  = (const float*)d_in[8];
    const float* W1  = (const float*)d_in[9];
    const float* bb1 = (const float*)d_in[10];
    const float* W2  = (const float*)d_in[11];
    const float* bb2 = (const float*)d_in[12];
    float* out = (float*)d_out;

    char* ws = (char*)d_ws;
    const size_t MB = 1024ull * 1024ull;
    u16* wqb   = (u16*)(ws + 0 * MB);
    u16* wkb   = (u16*)(ws + 2 * MB);
    u16* wvb   = (u16*)(ws + 4 * MB);
    u16* wob   = (u16*)(ws + 6 * MB);
    u16* w1b   = (u16*)(ws + 8 * MB);
    u16* w2b   = (u16*)(ws + 16 * MB);
    u16* xb    = (u16*)(ws + 24 * MB);
    u16* Qb    = (u16*)(ws + 40 * MB);
    u16* Kb    = (u16*)(ws + 56 * MB);
    u16* Vb    = (u16*)(ws + 72 * MB);
    u16* attnb = (u16*)(ws + 88 * MB);
    float* attno = (float*)(ws + 104 * MB);
    float* hbuf  = (float*)(ws + 136 * MB);
    u16* hb    = (u16*)(ws + 168 * MB);
    u16* ffn1  = (u16*)(ws + 24 * MB);
    float* y2  = (float*)(ws + 104 * MB);

    dim3 blk(256);
    auto cgrid = [](int n4) { int b = (n4 + 255) / 256; return dim3(b > 2048 ? 2048 : b); };

    cast_f32_bf16<<<cgrid(M_ROWS * E_DIM / 4), blk, 0, stream>>>(x, xb, M_ROWS * E_DIM / 4);
    cast_f32_bf16<<<cgrid(E_DIM * E_DIM / 4), blk, 0, stream>>>(Wq, wqb, E_DIM * E_DIM / 4);
    cast_f32_bf16<<<cgrid(E_DIM * E_DIM / 4), blk, 0, stream>>>(Wk, wkb, E_DIM * E_DIM / 4);
    cast_f32_bf16<<<cgrid(E_DIM * E_DIM / 4), blk, 0, stream>>>(Wv, wvb, E_DIM * E_DIM / 4);
    cast_f32_bf16<<<cgrid(E_DIM * E_DIM / 4), blk, 0, stream>>>(Wo, wob, E_DIM * E_DIM / 4);
    cast_f32_bf16<<<cgrid(F_DIM * E_DIM / 4), blk, 0, stream>>>(W1, w1b, F_DIM * E_DIM / 4);
    cast_f32_bf16<<<cgrid(E_DIM * F_DIM / 4), blk, 0, stream>>>(W2, w2b, E_DIM * F_DIM / 4);

    dim3 gEE(E_DIM / 128, M_ROWS / 128);
    gemm_bt<u16, false, false><<<gEE, blk, 0, stream>>>(xb, wqb, Qb, nullptr, M_ROWS, E_DIM, E_DIM);
    gemm_bt<u16, false, false><<<gEE, blk, 0, stream>>>(xb, wkb, Kb, nullptr, M_ROWS, E_DIM, E_DIM);
    gemm_bt<u16, false, false><<<gEE, blk, 0, stream>>>(xb, wvb, Vb, nullptr, M_ROWS, E_DIM, E_DIM);

    attn_kernel<<<dim3(S_LEN / 128, H_NUM, B_NUM), blk, 0, stream>>>(Qb, Kb, Vb, attnb);

    gemm_bt<float, false, false><<<gEE, blk, 0, stream>>>(attnb, wob, attno, nullptr, M_ROWS, E_DIM, E_DIM);

    add_ln<<<dim3(M_ROWS), blk, 0, stream>>>(x, attno, g1, b1, hbuf, hb);

    gemm_bt<u16, true, true><<<dim3(F_DIM / 128, M_ROWS / 128), blk, 0, stream>>>(hb, w1b, ffn1, bb1, M_ROWS, F_DIM, E_DIM);
    gemm_bt<float, false, true><<<gEE, blk, 0, stream>>>(ffn1, w2b, y2, bb2, M_ROWS, E_DIM, F_DIM);

    add_ln<<<dim3(M_ROWS), blk, 0, stream>>>(hbuf, y2, g2, b2, out, nullptr);
}

// Round 4
// 446.347 us; speedup vs baseline: 1.6179x; 1.1677x over previous
//
#include <hip/hip_runtime.h>
#include <stdint.h>

// ---------------- problem constants ----------------
#define E_DIM   1024
#define H_NUM   16
#define HD      64        // head dim
#define F_DIM   4096
#define B_NUM   4
#define S_LEN   2048
#define M_ROWS  (B_NUM * S_LEN)   // 8192
#define QKV_LD  3072              // fused QKV row stride (elems)

typedef unsigned short u16;
typedef __bf16 bf16_t;
typedef bf16_t  bf16x8 __attribute__((ext_vector_type(8)));
typedef u16     u16x8  __attribute__((ext_vector_type(8)));
typedef float   f32x4  __attribute__((ext_vector_type(4)));
typedef float   f32x16 __attribute__((ext_vector_type(16)));
typedef unsigned u32x4 __attribute__((ext_vector_type(4)));

#define AS1 __attribute__((address_space(1)))
#define AS3 __attribute__((address_space(3)))

__device__ __forceinline__ void gload_lds16(const void* g, void* l) {
    __builtin_amdgcn_global_load_lds((AS1 void*)g, (AS3 void*)l, 16, 0, 0);
}

// f32 -> bf16 RNE
__device__ __forceinline__ u16 f2b(float f) {
    union { float f; unsigned u; } a; a.f = f;
    unsigned u = a.u + 0x7fffu + ((a.u >> 16) & 1u);
    return (u16)(u >> 16);
}

__device__ __forceinline__ unsigned cvt_pk_bf16(float lo, float hi) {
    unsigned r;
    asm("v_cvt_pk_bf16_f32 %0, %1, %2" : "=v"(r) : "v"(lo), "v"(hi));
    return r;
}

// XOR swizzle for 32-row x 128B LDS tiles (attn K tile)
__device__ __forceinline__ int swz_c(int row) {
    return ((row & 7) << 4) ^ ((row & 8) << 2);
}
// XOR swizzle for 64-row x 64B LDS tiles (attn Vt tile)
__device__ __forceinline__ int swz_v(int row) {
    return ((row >> 1) & 3) << 4;
}

#define VM_WAIT(n) asm volatile("s_waitcnt vmcnt(" #n ")" ::: "memory")

// ---------------- cast kernel ----------------
__global__ __launch_bounds__(256) void cast_f32_bf16(const float* __restrict__ in,
                                                     u16* __restrict__ out, int n4) {
    int stride = gridDim.x * blockDim.x;
    for (int i = blockIdx.x * blockDim.x + threadIdx.x; i < n4; i += stride) {
        float4 v = reinterpret_cast<const float4*>(in)[i];
        ushort4 o;
        o.x = f2b(v.x); o.y = f2b(v.y); o.z = f2b(v.z); o.w = f2b(v.w);
        reinterpret_cast<ushort4*>(out)[i] = o;
    }
}

__device__ __forceinline__ void store_c(float* C, size_t idx, float v) { C[idx] = v; }
__device__ __forceinline__ void store_c(u16* C, size_t idx, float v)   { C[idx] = f2b(v); }

// ---------------- GEMM v2: C[M,N] = A[M,K] * B[N,K]^T ----------------
// BM=128, BN=256, BK=32. 512 thr = 8 waves (2M x 4N), 64x64 out per wave.
// Triple-buffered K-tiles (24KB each: A 8KB + B 16KB), prefetch distance 2,
// counted vmcnt (never 0 mid-loop), raw barriers (no vmcnt(0) drain).
// BK=32 => 64B LDS rows => fragment ds_read_b128 conflict-free (no swizzle).
template <typename OutT, bool RELU, bool HASBIAS, int K>
__global__ __launch_bounds__(512, 4)
void gemm2(const u16* __restrict__ A, const u16* __restrict__ B,
           OutT* __restrict__ C, const float* __restrict__ bias,
           int M, int N) {
    constexpr int NT = K / 32;
    __shared__ __align__(16) char smem[3 * 24576];

    const int tid  = threadIdx.x;
    const int lane = tid & 63, wave = tid >> 6;
    const int lr   = lane & 15, kh = lane >> 4;
    const int wr   = wave >> 2, wc = wave & 3;

    // XCD-chunked block swizzle (bijective: nwg % 8 == 0 for all our grids)
    const int nwg = gridDim.x * gridDim.y;
    int wg = blockIdx.y * gridDim.x + blockIdx.x;
    const int cpx = nwg >> 3;
    wg = (wg & 7) * cpx + (wg >> 3);
    const int bx = wg % gridDim.x, by = wg / gridDim.x;
    const int row0 = by * 128, col0 = bx * 256;

    // staging: thread covers 16B of a 64B row; 4 thr/row
    const int srow = tid >> 2, scolb = (tid & 3) * 16;
    const char* Ag  = (const char*)(A + (size_t)(row0 + srow) * K) + scolb;
    const char* Bg0 = (const char*)(B + (size_t)(col0 + srow) * K) + scolb;
    const char* Bg1 = (const char*)(B + (size_t)(col0 + 128 + srow) * K) + scolb;
    const int ldsw = wave * 1024;    // wave-uniform LDS base component

    auto stage = [&](int t) {
        char* s = smem + (t % 3) * 24576;
        const size_t ko = (size_t)t * 64;   // byte offset along K
        gload_lds16(Ag + ko,  s + ldsw);
        gload_lds16(Bg0 + ko, s + 8192 + ldsw);
        gload_lds16(Bg1 + ko, s + 16384 + ldsw);
    };

    f32x4 acc[4][4] = {};
    stage(0); stage(1);     // 6 vmem outstanding per wave

    for (int t = 0; t < NT; ++t) {
        if (t + 2 < NT) stage(t + 2);          // into slot (t+2)%3, dead since iter t-1
        if (t + 2 < NT)      VM_WAIT(6);        // drain tile t's 3 loads (FIFO)
        else if (t + 1 < NT) VM_WAIT(3);
        else                 VM_WAIT(0);
        __builtin_amdgcn_s_barrier();           // tile t visible to all waves
        __builtin_amdgcn_sched_barrier(0);

        const char* s = smem + (t % 3) * 24576;
        bf16x8 af[4], bf[4];
#pragma unroll
        for (int m = 0; m < 4; ++m)
            af[m] = *(const bf16x8*)(s + (wr * 64 + m * 16 + lr) * 64 + kh * 16);
#pragma unroll
        for (int n = 0; n < 4; ++n)
            bf[n] = *(const bf16x8*)(s + 8192 + (wc * 64 + n * 16 + lr) * 64 + kh * 16);

        __builtin_amdgcn_s_setprio(1);
#pragma unroll
        for (int m = 0; m < 4; ++m)
#pragma unroll
            for (int n = 0; n < 4; ++n)
                acc[m][n] = __builtin_amdgcn_mfma_f32_16x16x32_bf16(af[m], bf[n], acc[m][n], 0, 0, 0);
        __builtin_amdgcn_s_setprio(0);
        __builtin_amdgcn_sched_barrier(0);
        asm volatile("s_waitcnt lgkmcnt(0)" ::: "memory");
        __builtin_amdgcn_s_barrier();           // slot (t)%3 free for re-stage
    }

    // epilogue: C/D layout col=lane&15, row=(lane>>4)*4+reg
#pragma unroll
    for (int m = 0; m < 4; ++m) {
#pragma unroll
        for (int n = 0; n < 4; ++n) {
            int col = col0 + wc * 64 + n * 16 + lr;
            float bv = 0.f;
            if constexpr (HASBIAS) bv = bias[col];
#pragma unroll
            for (int r = 0; r < 4; ++r) {
                int row = row0 + wr * 64 + m * 16 + kh * 4 + r;
                float v = acc[m][n][r] + bv;
                if constexpr (RELU) v = fmaxf(v, 0.f);
                store_c(C, (size_t)row * N + col, v);
            }
        }
    }
}

// ---------------- flash attention, 32x32 swapped-QK structure ----------------
// Reads fused QKV buffer [M, 3072]: Q at col 0, K at col 1024, V at col 2048.
#define KVBLK 32
#define SC_LOG2E 0.1803368801111204f   // 0.125 * log2(e)

__global__ __launch_bounds__(256, 4)
void attn_kernel(const u16* __restrict__ QKV, u16* __restrict__ Ob) {
    __shared__ char Ks[2][KVBLK * 128];   // [kv][d] swizzled, 4KB each
    __shared__ char Vt[2][64 * 64];       // [d][kv] swizzled, 4KB each

    const int tid  = threadIdx.x;
    const int lane = tid & 63, wave = tid >> 6;
    const int l31  = lane & 31, hi = lane >> 5;
    const int q0   = blockIdx.x * 128;
    const int h    = blockIdx.y;
    const int b    = blockIdx.z;

    const u16* Q = QKV;
    const u16* Kp = QKV + 1024;
    const u16* V  = QKV + 2048;

    // ---- Q fragments: lane holds its q-row, the hi*8 half of each 16-d chunk
    const size_t qrow = (size_t)(b * S_LEN + q0 + wave * 32 + l31);
    bf16x8 qf[4];
#pragma unroll
    for (int c = 0; c < 4; ++c)
        qf[c] = *(const bf16x8*)(Q + qrow * QKV_LD + h * HD + c * 16 + hi * 8);

    f32x16 o0 = {}, o1 = {};
    float m_run = -1e30f, l_run = 0.f;

    const u16* Vg = V + (size_t)(b * S_LEN) * QKV_LD + h * HD;
    const char* Kg = (const char*)(Kp + (size_t)(b * S_LEN) * QKV_LD + h * HD);

    // K staging: wave w covers rows w*8..w*8+7 of the 32-row tile
    const int krow  = wave * 8 + (lane >> 3);
    const int kcolb = ((lane & 7) * 16) ^ swz_c(krow);

    u16 vst[8];
    // ---- prologue: stage tile 0
    gload_lds16(Kg + (size_t)krow * (QKV_LD * 2) + kcolb, Ks[0] + wave * 1024);
    {
        const u16* vp = Vg + (size_t)(wave * 8) * QKV_LD + lane;
#pragma unroll
        for (int i = 0; i < 8; ++i) vst[i] = vp[(size_t)i * QKV_LD];
        u16x8 vv;
#pragma unroll
        for (int i = 0; i < 8; ++i) vv[i] = vst[i];
        *(u16x8*)(Vt[0] + lane * 64 + ((wave * 16) ^ swz_v(lane))) = vv;
    }
    __syncthreads();

    const int NT = S_LEN / KVBLK;   // 64
    for (int t = 0; t < NT; ++t) {
        const int cur = t & 1;
        // ---- prefetch next tile
        if (t < NT - 1) {
            const int kv0n = (t + 1) * KVBLK;
            gload_lds16(Kg + (size_t)(kv0n + krow) * (QKV_LD * 2) + kcolb, Ks[cur ^ 1] + wave * 1024);
            const u16* vp = Vg + (size_t)(kv0n + wave * 8) * QKV_LD + lane;
#pragma unroll
            for (int i = 0; i < 8; ++i) vst[i] = vp[(size_t)i * QKV_LD];
        }

        // ---- S^T = K Q^T: 4 MFMAs over d-chunks
        f32x16 st = {};
#pragma unroll
        for (int c = 0; c < 4; ++c) {
            bf16x8 kf = *(const bf16x8*)(Ks[cur] + l31 * 128 + ((c * 32 + hi * 16) ^ swz_c(l31)));
            st = __builtin_amdgcn_mfma_f32_32x32x16_bf16(kf, qf[c], st, 0, 0, 0);
        }

        // ---- online softmax (lane owns q-col)
        float pm = st[0];
#pragma unroll
        for (int i = 1; i < 16; ++i) pm = fmaxf(pm, st[i]);
        pm = fmaxf(pm, __shfl_xor(pm, 32));
        if (__any(pm > m_run + 64.f)) {     // defer-max: THR=8 in ln-domain
            float mn = fmaxf(m_run, pm);
            float al = exp2f((m_run - mn) * SC_LOG2E);
#pragma unroll
            for (int r = 0; r < 16; ++r) { o0[r] *= al; o1[r] *= al; }
            l_run *= al;
            m_run = mn;
        }
        const float mc = m_run * SC_LOG2E;
        float p[16];
        float rs = 0.f;
#pragma unroll
        for (int i = 0; i < 16; ++i) {
            p[i] = exp2f(__builtin_fmaf(st[i], SC_LOG2E, -mc));
            rs += p[i];
        }
        rs += __shfl_xor(rs, 32);
        l_run += rs;

        // ---- pack P to bf16 pairs, exchange across the hi-split (T12)
        unsigned w[8], x[8];
#pragma unroll
        for (int i = 0; i < 8; ++i) w[i] = cvt_pk_bf16(p[2 * i], p[2 * i + 1]);
#pragma unroll
        for (int i = 0; i < 8; ++i) x[i] = __shfl_xor(w[i], 32);

        // ---- PV: O^T += V^T P^T
#pragma unroll
        for (int cc = 0; cc < 2; ++cc) {
            u32x4 fw;
            fw[0] = hi ? x[4 * cc + 2] : w[4 * cc];
            fw[1] = hi ? x[4 * cc + 3] : w[4 * cc + 1];
            fw[2] = hi ? w[4 * cc + 2] : x[4 * cc];
            fw[3] = hi ? w[4 * cc + 3] : x[4 * cc + 1];
            bf16x8 pf = __builtin_bit_cast(bf16x8, fw);
            bf16x8 v0 = *(const bf16x8*)(Vt[cur] + l31 * 64 + ((cc * 32 + hi * 16) ^ swz_v(l31)));
            bf16x8 v1 = *(const bf16x8*)(Vt[cur] + (32 + l31) * 64 + ((cc * 32 + hi * 16) ^ swz_v(32 + l31)));
            o0 = __builtin_amdgcn_mfma_f32_32x32x16_bf16(v0, pf, o0, 0, 0, 0);
            o1 = __builtin_amdgcn_mfma_f32_32x32x16_bf16(v1, pf, o1, 0, 0, 0);
        }

        // ---- write next Vt, then barrier
        if (t < NT - 1) {
            u16x8 vv;
#pragma unroll
            for (int i = 0; i < 8; ++i) vv[i] = vst[i];
            *(u16x8*)(Vt[cur ^ 1] + lane * 64 + ((wave * 16) ^ swz_v(lane))) = vv;
        }
        __syncthreads();
    }

    // ---- epilogue: normalize, merge hi-split halves, 4x dwordx4 store
    const float inv = 1.0f / l_run;
    unsigned m0[16], xx[16];
#pragma unroll
    for (int g = 0; g < 4; ++g)
#pragma unroll
        for (int u = 0; u < 2; ++u) {
            int r = g * 4 + 2 * u;
            m0[2 * g + u]     = cvt_pk_bf16(o0[r] * inv, o0[r + 1] * inv);
            m0[8 + 2 * g + u] = cvt_pk_bf16(o1[r] * inv, o1[r + 1] * inv);
        }
#pragma unroll
    for (int i = 0; i < 16; ++i) xx[i] = __shfl_xor(m0[i], 32);

    {
        unsigned full[8], sec[8];
#pragma unroll
        for (int g = 0; g < 4; ++g) {
            full[2 * g + 0] = hi ? xx[8 + 2 * g]     : m0[2 * g];
            full[2 * g + 1] = hi ? xx[8 + 2 * g + 1] : m0[2 * g + 1];
            sec[2 * g + 0]  = hi ? m0[8 + 2 * g]     : xx[2 * g];
            sec[2 * g + 1]  = hi ? m0[8 + 2 * g + 1] : xx[2 * g + 1];
        }
        u32x4 out0, out1, out2, out3;
        out0[0] = full[0]; out0[1] = full[1]; out0[2] = sec[0]; out0[3] = sec[1];
        out1[0] = full[2]; out1[1] = full[3]; out1[2] = sec[2]; out1[3] = sec[3];
        out2[0] = full[4]; out2[1] = full[5]; out2[2] = sec[4]; out2[3] = sec[5];
        out3[0] = full[6]; out3[1] = full[7]; out3[2] = sec[6]; out3[3] = sec[7];
        u16* op = Ob + qrow * E_DIM + h * HD + hi * 32;
        *(u32x4*)(op)      = out0;
        *(u32x4*)(op + 8)  = out1;
        *(u32x4*)(op + 16) = out2;
        *(u32x4*)(op + 24) = out3;
    }
}

// ---------------- fused residual add + LayerNorm ----------------
__global__ __launch_bounds__(256)
void add_ln(const float* __restrict__ xa, const float* __restrict__ xb2,
            const float* __restrict__ g, const float* __restrict__ be,
            float* __restrict__ of, u16* __restrict__ ob) {
    const int row = blockIdx.x;
    const int t = threadIdx.x;
    const int lane = t & 63, wave = t >> 6;

    float4 va = reinterpret_cast<const float4*>(xa + (size_t)row * E_DIM)[t];
    float4 vb = reinterpret_cast<const float4*>(xb2 + (size_t)row * E_DIM)[t];
    float v0 = va.x + vb.x, v1 = va.y + vb.y, v2 = va.z + vb.z, v3 = va.w + vb.w;
    float s  = v0 + v1 + v2 + v3;
    float s2 = v0 * v0 + v1 * v1 + v2 * v2 + v3 * v3;
#pragma unroll
    for (int m = 32; m >= 1; m >>= 1) {
        s  += __shfl_xor(s, m);
        s2 += __shfl_xor(s2, m);
    }
    __shared__ float red[8];
    if (lane == 0) { red[wave] = s; red[4 + wave] = s2; }
    __syncthreads();
    s  = red[0] + red[1] + red[2] + red[3];
    s2 = red[4] + red[5] + red[6] + red[7];

    float mu   = s * (1.0f / E_DIM);
    float var  = s2 * (1.0f / E_DIM) - mu * mu;
    float rstd = rsqrtf(var + 1e-5f);

    float4 gg = reinterpret_cast<const float4*>(g)[t];
    float4 bb = reinterpret_cast<const float4*>(be)[t];
    float y0 = (v0 - mu) * rstd * gg.x + bb.x;
    float y1 = (v1 - mu) * rstd * gg.y + bb.y;
    float y2 = (v2 - mu) * rstd * gg.z + bb.z;
    float y3 = (v3 - mu) * rstd * gg.w + bb.w;
    if (of) {
        float4 o; o.x = y0; o.y = y1; o.z = y2; o.w = y3;
        reinterpret_cast<float4*>(of + (size_t)row * E_DIM)[t] = o;
    }
    if (ob) {
        ushort4 o;
        o.x = f2b(y0); o.y = f2b(y1); o.z = f2b(y2); o.w = f2b(y3);
        reinterpret_cast<ushort4*>(ob + (size_t)row * E_DIM)[t] = o;
    }
}

// ---------------- launch ----------------
extern "C" void kernel_launch(void* const* d_in, const int* in_sizes, int n_in,
                              void* d_out, int out_size, void* d_ws, size_t ws_size,
                              hipStream_t stream) {
    const float* x   = (const float*)d_in[0];
    const float* Wq  = (const float*)d_in[1];
    const float* Wk  = (const float*)d_in[2];
    const float* Wv  = (const float*)d_in[3];
    const float* Wo  = (const float*)d_in[4];
    const float* g1  = (const float*)d_in[5];
    const float* b1  = (const float*)d_in[6];
    const float* g2  = (const float*)d_in[7];
    const float* b2  = (const float*)d_in[8];
    const float* W1  = (const float*)d_in[9];
    const float* bb1 = (const float*)d_in[10];
    const float* W2  = (const float*)d_in[11];
    const float* bb2 = (const float*)d_in[12];
    float* out = (float*)d_out;

    char* ws = (char*)d_ws;
    const size_t MB = 1024ull * 1024ull;
    u16* wqkvb = (u16*)(ws + 0 * MB);            // [3072,1024] bf16 = 6MB
    u16* wob   = (u16*)(ws + 6 * MB);
    u16* w1b   = (u16*)(ws + 8 * MB);
    u16* w2b   = (u16*)(ws + 16 * MB);
    u16* xb    = (u16*)(ws + 24 * MB);           // dead after QKV gemm
    u16* qkvb  = (u16*)(ws + 40 * MB);           // [8192,3072] = 48MB, dead after attn
    u16* attnb = (u16*)(ws + 88 * MB);           // dead after Wo gemm
    float* attno = (float*)(ws + 104 * MB);      // dead after LN1
    float* hbuf  = (float*)(ws + 136 * MB);
    u16* hb    = (u16*)(ws + 168 * MB);          // dead after FFN1
    u16* ffn1  = (u16*)(ws + 24 * MB);           // reuse xb/qkvb region (64MB)
    float* y2  = (float*)(ws + 104 * MB);        // reuse attno region

    dim3 blk(256);
    auto cgrid = [](int n4) { int b = (n4 + 255) / 256; return dim3(b > 2048 ? 2048 : b); };

    cast_f32_bf16<<<cgrid(M_ROWS * E_DIM / 4), blk, 0, stream>>>(x, xb, M_ROWS * E_DIM / 4);
    cast_f32_bf16<<<cgrid(E_DIM * E_DIM / 4), blk, 0, stream>>>(Wq, wqkvb, E_DIM * E_DIM / 4);
    cast_f32_bf16<<<cgrid(E_DIM * E_DIM / 4), blk, 0, stream>>>(Wk, wqkvb + E_DIM * E_DIM, E_DIM * E_DIM / 4);
    cast_f32_bf16<<<cgrid(E_DIM * E_DIM / 4), blk, 0, stream>>>(Wv, wqkvb + 2 * E_DIM * E_DIM, E_DIM * E_DIM / 4);
    cast_f32_bf16<<<cgrid(E_DIM * E_DIM / 4), blk, 0, stream>>>(Wo, wob, E_DIM * E_DIM / 4);
    cast_f32_bf16<<<cgrid(F_DIM * E_DIM / 4), blk, 0, stream>>>(W1, w1b, F_DIM * E_DIM / 4);
    cast_f32_bf16<<<cgrid(E_DIM * F_DIM / 4), blk, 0, stream>>>(W2, w2b, E_DIM * F_DIM / 4);

    dim3 blk5(512);
    // QKV fused: [8192,3072] = xb @ Wqkv^T
    gemm2<u16, false, false, E_DIM><<<dim3(QKV_LD / 256, M_ROWS / 128), blk5, 0, stream>>>(
        xb, wqkvb, qkvb, nullptr, M_ROWS, QKV_LD);

    attn_kernel<<<dim3(S_LEN / 128, H_NUM, B_NUM), blk, 0, stream>>>(qkvb, attnb);

    gemm2<float, false, false, E_DIM><<<dim3(E_DIM / 256, M_ROWS / 128), blk5, 0, stream>>>(
        attnb, wob, attno, nullptr, M_ROWS, E_DIM);

    add_ln<<<dim3(M_ROWS), blk, 0, stream>>>(x, attno, g1, b1, hbuf, hb);

    gemm2<u16, true, true, E_DIM><<<dim3(F_DIM / 256, M_ROWS / 128), blk5, 0, stream>>>(
        hb, w1b, ffn1, bb1, M_ROWS, F_DIM);

    gemm2<float, false, true, F_DIM><<<dim3(E_DIM / 256, M_ROWS / 128), blk5, 0, stream>>>(
        ffn1, w2b, y2, bb2, M_ROWS, E_DIM);

    add_ln<<<dim3(M_ROWS), blk, 0, stream>>>(hbuf, y2, g2, b2, out, nullptr);
}